// Round 1
// baseline (335.711 us; speedup 1.0000x reference)
//
#include <hip/hip_runtime.h>

typedef __attribute__((ext_vector_type(8))) __bf16 bf16x8;
typedef __attribute__((ext_vector_type(4))) float f32x4;
typedef unsigned short u16;
typedef unsigned int u32;

__device__ __forceinline__ u16 f2bf(float f) {
  u32 u = __float_as_uint(f);
  u += 0x7fffu + ((u >> 16) & 1u);
  return (u16)(u >> 16);
}
__device__ __forceinline__ float bf2f(u16 h) {
  return __uint_as_float(((u32)h) << 16);
}
__device__ __forceinline__ f32x4 mfma16(bf16x8 a, bf16x8 b, f32x4 c) {
  return __builtin_amdgcn_mfma_f32_16x16x32_bf16(a, b, c, 0, 0, 0);
}

// ---------------- converts ----------------
__global__ void cvt_to_bf16(const float* __restrict__ src, u16* __restrict__ dst, int n) {
  const int i = (blockIdx.x * 256 + threadIdx.x) * 4;
  if (i + 3 < n) {
    const float4 v = *(const float4*)(src + i);
    ushort4 o; o.x = f2bf(v.x); o.y = f2bf(v.y); o.z = f2bf(v.z); o.w = f2bf(v.w);
    *(ushort4*)(dst + i) = o;
  }
}

// dst[C x R] = bf16(src[R x C])^T
__global__ void transpose_to_bf16(const float* __restrict__ src, u16* __restrict__ dst,
                                  int R, int C) {
  __shared__ float tile[32][33];
  const int c0 = blockIdx.x * 32, r0 = blockIdx.y * 32;
  const int tx = threadIdx.x, ty = threadIdx.y;
  for (int i = ty; i < 32; i += 8)
    tile[i][tx] = src[(size_t)(r0 + i) * C + c0 + tx];
  __syncthreads();
  for (int i = ty; i < 32; i += 8)
    dst[(size_t)(c0 + i) * R + r0 + tx] = f2bf(tile[tx][i]);
}

// ---------------- GEMM: C[MxN] = A[Mx512] * Bt[Nx512]^T, K=512 ----------------
// MODE 0: QK-producer  (A=wT rows 0..1023, Bt=xb).  i = feature f in [0,1024), j = token.
// MODE 1: V-producer   (A=xb, Bt=wT rows 1024..1535). i = token, j = v-feature in [0,512).
// MODE 2: proj         (A=wpT, Bt=attn_out). i = out-feature c, j = token. fp32 out + bias.
template<int MODE>
__global__ __launch_bounds__(256, 2) void gemm_bt(
    const u16* __restrict__ A, const u16* __restrict__ Bt,
    u16* __restrict__ out0, u16* __restrict__ out1,
    float* __restrict__ fout, const float* __restrict__ bias)
{
  __shared__ u16 As[128][40];   // 32 data + 8 pad halves -> 80B rows (2-way banks)
  __shared__ u16 Bs[128][40];
  const int tid = threadIdx.x;
  const int w = tid >> 6, l = tid & 63;
  const int lr = l & 15, lg = l >> 4;
  const int wr = w >> 1, wc = w & 1;
  const int m0 = blockIdx.y * 128, n0 = blockIdx.x * 128;

  f32x4 acc[4][4] = {};

  for (int k0 = 0; k0 < 512; k0 += 32) {
    int4 ra[2], rb[2];
#pragma unroll
    for (int it = 0; it < 2; ++it) {
      const int ch = it * 256 + tid;
      const int row = ch >> 2, c = ch & 3;
      ra[it] = *(const int4*)(A  + (size_t)(m0 + row) * 512 + k0 + c * 8);
      rb[it] = *(const int4*)(Bt + (size_t)(n0 + row) * 512 + k0 + c * 8);
    }
    __syncthreads();
#pragma unroll
    for (int it = 0; it < 2; ++it) {
      const int ch = it * 256 + tid;
      const int row = ch >> 2, c = ch & 3;
      *(int4*)&As[row][c * 8] = ra[it];
      *(int4*)&Bs[row][c * 8] = rb[it];
    }
    __syncthreads();
    bf16x8 af[4], bfr[4];
#pragma unroll
    for (int mi = 0; mi < 4; ++mi)
      af[mi] = *(const bf16x8*)&As[wr * 64 + mi * 16 + lr][lg * 8];
#pragma unroll
    for (int nj = 0; nj < 4; ++nj)
      bfr[nj] = *(const bf16x8*)&Bs[wc * 64 + nj * 16 + lr][lg * 8];
#pragma unroll
    for (int mi = 0; mi < 4; ++mi)
#pragma unroll
      for (int nj = 0; nj < 4; ++nj)
        acc[mi][nj] = mfma16(af[mi], bfr[nj], acc[mi][nj]);
  }

#pragma unroll
  for (int mi = 0; mi < 4; ++mi)
#pragma unroll
    for (int nj = 0; nj < 4; ++nj) {
      const int i0 = m0 + wr * 64 + mi * 16 + lg * 4;  // 4 consecutive i
      const int j  = n0 + wc * 64 + nj * 16 + lr;
      if (MODE == 0) {
        const int bb = j >> 10, n = j & 1023;
        const bool isQ = i0 < 512;
        const int f = isQ ? i0 : i0 - 512;
        const int h = f >> 6, d = f & 63;
        const float scl = isQ ? 0.125f : 1.0f;
        u16* dst = isQ ? out0 : out1;
        ushort4 o;
        o.x = f2bf(acc[mi][nj][0] * scl); o.y = f2bf(acc[mi][nj][1] * scl);
        o.z = f2bf(acc[mi][nj][2] * scl); o.w = f2bf(acc[mi][nj][3] * scl);
        *(ushort4*)(dst + ((size_t)((bb * 8 + h) * 1024 + n)) * 64 + d) = o;
      } else if (MODE == 1) {
        const int bb = i0 >> 10, nloc = i0 & 1023;
        const int h = j >> 6, d = j & 63;
        ushort4 o;
        o.x = f2bf(acc[mi][nj][0]); o.y = f2bf(acc[mi][nj][1]);
        o.z = f2bf(acc[mi][nj][2]); o.w = f2bf(acc[mi][nj][3]);
        *(ushort4*)(out0 + ((size_t)((bb * 8 + h) * 64 + d)) * 1024 + nloc) = o;
      } else {
        const float4 bp = *(const float4*)(bias + i0);
        float4 o;
        o.x = acc[mi][nj][0] + bp.x; o.y = acc[mi][nj][1] + bp.y;
        o.z = acc[mi][nj][2] + bp.z; o.w = acc[mi][nj][3] + bp.w;
        *(float4*)(fout + (size_t)j * 512 + i0) = o;
      }
    }
}

// ---------------- flash attention ----------------
// grid = B*32 blocks (one per (b, 32-row q-tile)), 512 threads = 8 waves = 8 heads.
__global__ __launch_bounds__(512, 2) void flash_attn(
    const u16* __restrict__ Q, const u16* __restrict__ Kg,
    const u16* __restrict__ Vt, const int* __restrict__ ids_keep,
    const int* __restrict__ rel_index, const float* __restrict__ rel_table,
    u16* __restrict__ attn_out)
{
  __shared__ u16 Ks[8][32][72];   // per head: K tile [m][d], 144B rows
  __shared__ u16 Vs[8][64][40];   // per head: Vt tile [d][m], 80B rows
  __shared__ u16 Ps[8][32][40];   // per head: P tile [n][m], 80B rows
  __shared__ u16 Bi[8][32][33];   // bias, bf16, [h][n][m]
  __shared__ int ids_s[1024];

  const int bb = blockIdx.x >> 5;
  const int n0 = (blockIdx.x & 31) << 5;
  const int tid = threadIdx.x;
  const int w = tid >> 6;
  const int l = tid & 63;
  const int lr = l & 15, lg = l >> 4;

  ids_s[tid]       = ids_keep[bb * 1024 + tid];
  ids_s[tid + 512] = ids_keep[bb * 1024 + tid + 512];

  const size_t hbase = (size_t)(bb * 8 + w) * (1024 * 64);

  bf16x8 qf[2][2];
#pragma unroll
  for (int mi = 0; mi < 2; ++mi)
#pragma unroll
    for (int ki = 0; ki < 2; ++ki)
      qf[mi][ki] = *(const bf16x8*)(Q + hbase + (size_t)(n0 + mi * 16 + lr) * 64 + ki * 32 + lg * 8);

  f32x4 acc[2][4] = {};
  float mrow[2][4], lsum[2][4];
#pragma unroll
  for (int mi = 0; mi < 2; ++mi)
#pragma unroll
    for (int r = 0; r < 4; ++r) { mrow[mi][r] = -1e30f; lsum[mi][r] = 0.f; }

  __syncthreads();

  for (int t = 0; t < 32; ++t) {
    const int m0 = t << 5;
    // stage K (32x64) and Vt (64x32) for own head into regs
    int4 kreg[4], vreg[4];
#pragma unroll
    for (int i = 0; i < 4; ++i) {
      const int ch = i * 64 + l;
      kreg[i] = *(const int4*)(Kg + hbase + (size_t)(m0 + (ch >> 3)) * 64 + (ch & 7) * 8);
      vreg[i] = *(const int4*)(Vt + hbase + (size_t)(ch >> 2) * 1024 + m0 + (ch & 3) * 8);
    }
    // cooperative bias gather: 1024 (n,m) pairs, shared by all heads
    float4 tga[2], tgb[2];
    int pn[2], pm[2];
#pragma unroll
    for (int s2 = 0; s2 < 2; ++s2) {
      const int p = tid + s2 * 512;
      pn[s2] = p >> 5; pm[s2] = p & 31;
      const int idx = rel_index[(size_t)ids_s[n0 + pn[s2]] * 4096 + ids_s[m0 + pm[s2]]];
      tga[s2] = *(const float4*)(rel_table + (size_t)idx * 8);
      tgb[s2] = *(const float4*)(rel_table + (size_t)idx * 8 + 4);
    }
#pragma unroll
    for (int i = 0; i < 4; ++i) {
      const int ch = i * 64 + l;
      *(int4*)&Ks[w][ch >> 3][(ch & 7) * 8] = kreg[i];
      *(int4*)&Vs[w][ch >> 2][(ch & 3) * 8] = vreg[i];
    }
#pragma unroll
    for (int s2 = 0; s2 < 2; ++s2) {
      const int n = pn[s2], m = pm[s2];
      Bi[0][n][m] = f2bf(tga[s2].x);
      Bi[1][n][m] = f2bf(tga[s2].y);
      Bi[2][n][m] = f2bf(tga[s2].z);
      Bi[3][n][m] = f2bf(tga[s2].w);
      Bi[4][n][m] = f2bf(tgb[s2].x);
      Bi[5][n][m] = f2bf(tgb[s2].y);
      Bi[6][n][m] = f2bf(tgb[s2].z);
      Bi[7][n][m] = f2bf(tgb[s2].w);
    }
    __syncthreads();

    // QK^T: S[32n][32m]
    bf16x8 kf[2][2];
#pragma unroll
    for (int mj = 0; mj < 2; ++mj)
#pragma unroll
      for (int ki = 0; ki < 2; ++ki)
        kf[mj][ki] = *(const bf16x8*)&Ks[w][mj * 16 + lr][ki * 32 + lg * 8];

    f32x4 sc[2][2];
#pragma unroll
    for (int mi = 0; mi < 2; ++mi)
#pragma unroll
      for (int mj = 0; mj < 2; ++mj) {
        f32x4 z = {};
        z = mfma16(qf[mi][0], kf[mj][0], z);
        sc[mi][mj] = mfma16(qf[mi][1], kf[mj][1], z);
      }
#pragma unroll
    for (int mi = 0; mi < 2; ++mi)
#pragma unroll
      for (int mj = 0; mj < 2; ++mj)
#pragma unroll
        for (int r = 0; r < 4; ++r)
          sc[mi][mj][r] += bf2f(Bi[w][mi * 16 + lg * 4 + r][mj * 16 + lr]);

    // online softmax (per-row over 16 lanes of the row group)
#pragma unroll
    for (int mi = 0; mi < 2; ++mi) {
      float tm[4], co[4], ts[4];
#pragma unroll
      for (int r = 0; r < 4; ++r) {
        tm[r] = fmaxf(sc[mi][0][r], sc[mi][1][r]);
#pragma unroll
        for (int off = 1; off < 16; off <<= 1)
          tm[r] = fmaxf(tm[r], __shfl_xor(tm[r], off));
        const float mn = fmaxf(mrow[mi][r], tm[r]);
        co[r] = __expf(mrow[mi][r] - mn);
        mrow[mi][r] = mn;
      }
#pragma unroll
      for (int mj = 0; mj < 2; ++mj)
#pragma unroll
        for (int r = 0; r < 4; ++r)
          sc[mi][mj][r] = __expf(sc[mi][mj][r] - mrow[mi][r]);
#pragma unroll
      for (int r = 0; r < 4; ++r) {
        ts[r] = sc[mi][0][r] + sc[mi][1][r];
#pragma unroll
        for (int off = 1; off < 16; off <<= 1)
          ts[r] += __shfl_xor(ts[r], off);
        lsum[mi][r] = lsum[mi][r] * co[r] + ts[r];
      }
#pragma unroll
      for (int dj = 0; dj < 4; ++dj)
#pragma unroll
        for (int r = 0; r < 4; ++r)
          acc[mi][dj][r] *= co[r];
    }

    // P -> LDS (D-frag layout -> A-frag layout)
#pragma unroll
    for (int mi = 0; mi < 2; ++mi)
#pragma unroll
      for (int mj = 0; mj < 2; ++mj)
#pragma unroll
        for (int r = 0; r < 4; ++r)
          Ps[w][mi * 16 + lg * 4 + r][mj * 16 + lr] = f2bf(sc[mi][mj][r]);

    // PV
    bf16x8 pa[2], vfr[4];
#pragma unroll
    for (int mi = 0; mi < 2; ++mi)
      pa[mi] = *(const bf16x8*)&Ps[w][mi * 16 + lr][lg * 8];
#pragma unroll
    for (int dj = 0; dj < 4; ++dj)
      vfr[dj] = *(const bf16x8*)&Vs[w][dj * 16 + lr][lg * 8];
#pragma unroll
    for (int mi = 0; mi < 2; ++mi)
#pragma unroll
      for (int dj = 0; dj < 4; ++dj)
        acc[mi][dj] = mfma16(pa[mi], vfr[dj], acc[mi][dj]);

    __syncthreads();
  }

#pragma unroll
  for (int mi = 0; mi < 2; ++mi)
#pragma unroll
    for (int dj = 0; dj < 4; ++dj)
#pragma unroll
      for (int r = 0; r < 4; ++r) {
        const float v = acc[mi][dj][r] / lsum[mi][r];
        attn_out[(size_t)(bb * 1024 + n0 + mi * 16 + lg * 4 + r) * 512 + w * 64 + dj * 16 + lr] = f2bf(v);
      }
}

// ---------------- launch ----------------
extern "C" void kernel_launch(void* const* d_in, const int* in_sizes, int n_in,
                              void* d_out, int out_size, void* d_ws, size_t ws_size,
                              hipStream_t stream) {
  const float* x        = (const float*)d_in[0];
  const int*   ids      = (const int*)d_in[1];
  const float* w_qkv    = (const float*)d_in[2];
  const float* w_proj   = (const float*)d_in[3];
  const float* b_proj   = (const float*)d_in[4];
  const float* rel_tab  = (const float*)d_in[5];
  const int*   rel_idx  = (const int*)d_in[6];
  float* out = (float*)d_out;

  char* ws = (char*)d_ws;
  u16* xb   = (u16*)(ws);              // 8192x512 bf16 (8.39MB); later reused as attn_out
  u16* wT   = (u16*)(ws + 8388608);    // 1536x512 bf16
  u16* wpT  = (u16*)(ws + 9961472);    // 512x512 bf16
  u16* Qb   = (u16*)(ws + 10485760);   // (B,H,N,D) bf16, pre-scaled by 1/8
  u16* Kb   = (u16*)(ws + 18874368);   // (B,H,N,D) bf16
  u16* Vtb  = (u16*)(ws + 27262976);   // (B,H,D,N) bf16
  u16* attn = xb;                      // alias: xb dead after gemms

  cvt_to_bf16<<<4096, 256, 0, stream>>>(x, xb, 8 * 1024 * 512);
  transpose_to_bf16<<<dim3(48, 16), dim3(32, 8), 0, stream>>>(w_qkv, wT, 512, 1536);
  transpose_to_bf16<<<dim3(16, 16), dim3(32, 8), 0, stream>>>(w_proj, wpT, 512, 512);

  gemm_bt<0><<<dim3(64, 8), 256, 0, stream>>>(wT, xb, Qb, Kb, nullptr, nullptr);
  gemm_bt<1><<<dim3(4, 64), 256, 0, stream>>>(xb, wT + 1024 * 512, Vtb, nullptr, nullptr, nullptr);

  flash_attn<<<dim3(256), 512, 0, stream>>>(Qb, Kb, Vtb, ids, rel_idx, rel_tab, attn);

  gemm_bt<2><<<dim3(64, 4), 256, 0, stream>>>(wpT, attn, nullptr, nullptr, out, b_proj);
}

// Round 2
// 260.329 us; speedup vs baseline: 1.2896x; 1.2896x over previous
//
#include <hip/hip_runtime.h>

typedef __attribute__((ext_vector_type(8))) __bf16 bf16x8;
typedef __attribute__((ext_vector_type(4))) float f32x4;
typedef unsigned short u16;
typedef unsigned int u32;

__device__ __forceinline__ u16 f2bf(float f) {
  u32 u = __float_as_uint(f);
  u += 0x7fffu + ((u >> 16) & 1u);
  return (u16)(u >> 16);
}
__device__ __forceinline__ float bf2f(u16 h) {
  return __uint_as_float(((u32)h) << 16);
}
__device__ __forceinline__ f32x4 mfma16(bf16x8 a, bf16x8 b, f32x4 c) {
  return __builtin_amdgcn_mfma_f32_16x16x32_bf16(a, b, c, 0, 0, 0);
}

// ---------------- converts ----------------
__global__ void cvt_to_bf16(const float* __restrict__ src, u16* __restrict__ dst, int n) {
  const int i = (blockIdx.x * 256 + threadIdx.x) * 4;
  if (i + 3 < n) {
    const float4 v = *(const float4*)(src + i);
    ushort4 o; o.x = f2bf(v.x); o.y = f2bf(v.y); o.z = f2bf(v.z); o.w = f2bf(v.w);
    *(ushort4*)(dst + i) = o;
  }
}

// dst[C x R] = bf16(src[R x C])^T
__global__ void transpose_to_bf16(const float* __restrict__ src, u16* __restrict__ dst,
                                  int R, int C) {
  __shared__ float tile[32][33];
  const int c0 = blockIdx.x * 32, r0 = blockIdx.y * 32;
  const int tx = threadIdx.x, ty = threadIdx.y;
  for (int i = ty; i < 32; i += 8)
    tile[i][tx] = src[(size_t)(r0 + i) * C + c0 + tx];
  __syncthreads();
  for (int i = ty; i < 32; i += 8)
    dst[(size_t)(c0 + i) * R + r0 + tx] = f2bf(tile[tx][i]);
}

// ---------------- GEMM: C[MxN] = A[Mx512] * Bt[Nx512]^T, K=512 ----------------
template<int MODE>
__global__ __launch_bounds__(256, 2) void gemm_bt(
    const u16* __restrict__ A, const u16* __restrict__ Bt,
    u16* __restrict__ out0, u16* __restrict__ out1,
    float* __restrict__ fout, const float* __restrict__ bias)
{
  __shared__ u16 As[128][40];
  __shared__ u16 Bs[128][40];
  const int tid = threadIdx.x;
  const int w = tid >> 6, l = tid & 63;
  const int lr = l & 15, lg = l >> 4;
  const int wr = w >> 1, wc = w & 1;
  const int m0 = blockIdx.y * 128, n0 = blockIdx.x * 128;

  f32x4 acc[4][4] = {};

  for (int k0 = 0; k0 < 512; k0 += 32) {
    int4 ra[2], rb[2];
#pragma unroll
    for (int it = 0; it < 2; ++it) {
      const int ch = it * 256 + tid;
      const int row = ch >> 2, c = ch & 3;
      ra[it] = *(const int4*)(A  + (size_t)(m0 + row) * 512 + k0 + c * 8);
      rb[it] = *(const int4*)(Bt + (size_t)(n0 + row) * 512 + k0 + c * 8);
    }
    __syncthreads();
#pragma unroll
    for (int it = 0; it < 2; ++it) {
      const int ch = it * 256 + tid;
      const int row = ch >> 2, c = ch & 3;
      *(int4*)&As[row][c * 8] = ra[it];
      *(int4*)&Bs[row][c * 8] = rb[it];
    }
    __syncthreads();
    bf16x8 af[4], bfr[4];
#pragma unroll
    for (int mi = 0; mi < 4; ++mi)
      af[mi] = *(const bf16x8*)&As[wr * 64 + mi * 16 + lr][lg * 8];
#pragma unroll
    for (int nj = 0; nj < 4; ++nj)
      bfr[nj] = *(const bf16x8*)&Bs[wc * 64 + nj * 16 + lr][lg * 8];
#pragma unroll
    for (int mi = 0; mi < 4; ++mi)
#pragma unroll
      for (int nj = 0; nj < 4; ++nj)
        acc[mi][nj] = mfma16(af[mi], bfr[nj], acc[mi][nj]);
  }

#pragma unroll
  for (int mi = 0; mi < 4; ++mi)
#pragma unroll
    for (int nj = 0; nj < 4; ++nj) {
      const int i0 = m0 + wr * 64 + mi * 16 + lg * 4;
      const int j  = n0 + wc * 64 + nj * 16 + lr;
      if (MODE == 0) {
        const int bb = j >> 10, n = j & 1023;
        const bool isQ = i0 < 512;
        const int f = isQ ? i0 : i0 - 512;
        const int h = f >> 6, d = f & 63;
        const float scl = isQ ? 0.125f : 1.0f;
        u16* dst = isQ ? out0 : out1;
        ushort4 o;
        o.x = f2bf(acc[mi][nj][0] * scl); o.y = f2bf(acc[mi][nj][1] * scl);
        o.z = f2bf(acc[mi][nj][2] * scl); o.w = f2bf(acc[mi][nj][3] * scl);
        *(ushort4*)(dst + ((size_t)((bb * 8 + h) * 1024 + n)) * 64 + d) = o;
      } else if (MODE == 1) {
        const int bb = i0 >> 10, nloc = i0 & 1023;
        const int h = j >> 6, d = j & 63;
        ushort4 o;
        o.x = f2bf(acc[mi][nj][0]); o.y = f2bf(acc[mi][nj][1]);
        o.z = f2bf(acc[mi][nj][2]); o.w = f2bf(acc[mi][nj][3]);
        *(ushort4*)(out0 + ((size_t)((bb * 8 + h) * 64 + d)) * 1024 + nloc) = o;
      } else {
        const float4 bp = *(const float4*)(bias + i0);
        float4 o;
        o.x = acc[mi][nj][0] + bp.x; o.y = acc[mi][nj][1] + bp.y;
        o.z = acc[mi][nj][2] + bp.z; o.w = acc[mi][nj][3] + bp.w;
        *(float4*)(fout + (size_t)j * 512 + i0) = o;
      }
    }
}

// ---------------- flash attention ----------------
// grid = B*32 blocks (one per (b, 32-row q-tile)), 512 threads = 8 waves = 8 heads.
// Bias index computed arithmetically: idx = code[n] - code[m] + 8064,
// code(p) = (p>>6)*127 + (p&63). No rel_index table reads.
__global__ __launch_bounds__(512, 2) void flash_attn(
    const u16* __restrict__ Q, const u16* __restrict__ Kg,
    const u16* __restrict__ Vt, const int* __restrict__ ids_keep,
    const float* __restrict__ rel_table,
    u16* __restrict__ attn_out)
{
  __shared__ u16 Ps[8][32][40];   // per head: P tile [n][m], 80B rows
  __shared__ u16 Bi[8][32][34];   // bias, bf16, [h][n][m]
  __shared__ int codes_s[1024];

  const int bb = blockIdx.x >> 5;
  const int n0 = (blockIdx.x & 31) << 5;
  const int tid = threadIdx.x;
  const int w = tid >> 6;
  const int l = tid & 63;
  const int lr = l & 15, lg = l >> 4;

  {
    const int id0 = ids_keep[bb * 1024 + tid];
    const int id1 = ids_keep[bb * 1024 + tid + 512];
    codes_s[tid]       = (id0 >> 6) * 127 + (id0 & 63);
    codes_s[tid + 512] = (id1 >> 6) * 127 + (id1 & 63);
  }

  const size_t hbase = (size_t)(bb * 8 + w) * (1024 * 64);

  bf16x8 qf[2][2];
#pragma unroll
  for (int mi = 0; mi < 2; ++mi)
#pragma unroll
    for (int ki = 0; ki < 2; ++ki)
      qf[mi][ki] = *(const bf16x8*)(Q + hbase + (size_t)(n0 + mi * 16 + lr) * 64 + ki * 32 + lg * 8);

  f32x4 acc[2][4] = {};
  float mrow[2][4], lsum[2][4];
#pragma unroll
  for (int mi = 0; mi < 2; ++mi)
#pragma unroll
    for (int r = 0; r < 4; ++r) { mrow[mi][r] = -1e30f; lsum[mi][r] = 0.f; }

  __syncthreads();

  for (int t = 0; t < 32; ++t) {
    const int m0 = t << 5;

    // direct K/V fragment loads from global (each element consumed once; L2-served)
    bf16x8 kf[2][2], vf[4];
#pragma unroll
    for (int mj = 0; mj < 2; ++mj)
#pragma unroll
      for (int ki = 0; ki < 2; ++ki)
        kf[mj][ki] = *(const bf16x8*)(Kg + hbase + (size_t)(m0 + mj * 16 + lr) * 64 + ki * 32 + lg * 8);
#pragma unroll
    for (int dj = 0; dj < 4; ++dj)
      vf[dj] = *(const bf16x8*)(Vt + hbase + (size_t)(dj * 16 + lr) * 1024 + m0 + lg * 8);

    // cooperative bias gather: 1024 (n,m) pairs shared by all 8 heads.
    float4 tga[2], tgb[2];
    int pn[2], pm[2];
#pragma unroll
    for (int s2 = 0; s2 < 2; ++s2) {
      const int p = tid + s2 * 512;
      pn[s2] = p >> 5; pm[s2] = p & 31;
      const int idx = codes_s[n0 + pn[s2]] - codes_s[m0 + pm[s2]] + 8064;
      tga[s2] = *(const float4*)(rel_table + (size_t)idx * 8);
      tgb[s2] = *(const float4*)(rel_table + (size_t)idx * 8 + 4);
    }

    __syncthreads();   // previous iteration's Bi reads complete

#pragma unroll
    for (int s2 = 0; s2 < 2; ++s2) {
      const int n = pn[s2], m = pm[s2];
      Bi[0][n][m] = f2bf(tga[s2].x);
      Bi[1][n][m] = f2bf(tga[s2].y);
      Bi[2][n][m] = f2bf(tga[s2].z);
      Bi[3][n][m] = f2bf(tga[s2].w);
      Bi[4][n][m] = f2bf(tgb[s2].x);
      Bi[5][n][m] = f2bf(tgb[s2].y);
      Bi[6][n][m] = f2bf(tgb[s2].z);
      Bi[7][n][m] = f2bf(tgb[s2].w);
    }

    // QK^T: S[32n][32m]
    f32x4 sc[2][2];
#pragma unroll
    for (int mi = 0; mi < 2; ++mi)
#pragma unroll
      for (int mj = 0; mj < 2; ++mj) {
        f32x4 z = {};
        z = mfma16(qf[mi][0], kf[mj][0], z);
        sc[mi][mj] = mfma16(qf[mi][1], kf[mj][1], z);
      }

    __syncthreads();   // Bi ready

#pragma unroll
    for (int mi = 0; mi < 2; ++mi)
#pragma unroll
      for (int mj = 0; mj < 2; ++mj)
#pragma unroll
        for (int r = 0; r < 4; ++r)
          sc[mi][mj][r] += bf2f(Bi[w][mi * 16 + lg * 4 + r][mj * 16 + lr]);

    // online softmax (per-row over 16 lanes)
#pragma unroll
    for (int mi = 0; mi < 2; ++mi) {
      float tm[4], co[4], ts[4];
#pragma unroll
      for (int r = 0; r < 4; ++r) {
        tm[r] = fmaxf(sc[mi][0][r], sc[mi][1][r]);
#pragma unroll
        for (int off = 1; off < 16; off <<= 1)
          tm[r] = fmaxf(tm[r], __shfl_xor(tm[r], off));
        const float mn = fmaxf(mrow[mi][r], tm[r]);
        co[r] = __expf(mrow[mi][r] - mn);
        mrow[mi][r] = mn;
      }
#pragma unroll
      for (int mj = 0; mj < 2; ++mj)
#pragma unroll
        for (int r = 0; r < 4; ++r)
          sc[mi][mj][r] = __expf(sc[mi][mj][r] - mrow[mi][r]);
#pragma unroll
      for (int r = 0; r < 4; ++r) {
        ts[r] = sc[mi][0][r] + sc[mi][1][r];
#pragma unroll
        for (int off = 1; off < 16; off <<= 1)
          ts[r] += __shfl_xor(ts[r], off);
        lsum[mi][r] = lsum[mi][r] * co[r] + ts[r];
      }
#pragma unroll
      for (int dj = 0; dj < 4; ++dj)
#pragma unroll
        for (int r = 0; r < 4; ++r)
          acc[mi][dj][r] *= co[r];
    }

    // P -> LDS (D-frag layout -> A-frag layout), wave-local
#pragma unroll
    for (int mi = 0; mi < 2; ++mi)
#pragma unroll
      for (int mj = 0; mj < 2; ++mj)
#pragma unroll
        for (int r = 0; r < 4; ++r)
          Ps[w][mi * 16 + lg * 4 + r][mj * 16 + lr] = f2bf(sc[mi][mj][r]);

    // PV
    bf16x8 pa[2];
#pragma unroll
    for (int mi = 0; mi < 2; ++mi)
      pa[mi] = *(const bf16x8*)&Ps[w][mi * 16 + lr][lg * 8];
#pragma unroll
    for (int mi = 0; mi < 2; ++mi)
#pragma unroll
      for (int dj = 0; dj < 4; ++dj)
        acc[mi][dj] = mfma16(pa[mi], vf[dj], acc[mi][dj]);
  }

#pragma unroll
  for (int mi = 0; mi < 2; ++mi)
#pragma unroll
    for (int dj = 0; dj < 4; ++dj)
#pragma unroll
      for (int r = 0; r < 4; ++r) {
        const float v = acc[mi][dj][r] / lsum[mi][r];
        attn_out[(size_t)(bb * 1024 + n0 + mi * 16 + lg * 4 + r) * 512 + w * 64 + dj * 16 + lr] = f2bf(v);
      }
}

// ---------------- launch ----------------
extern "C" void kernel_launch(void* const* d_in, const int* in_sizes, int n_in,
                              void* d_out, int out_size, void* d_ws, size_t ws_size,
                              hipStream_t stream) {
  const float* x        = (const float*)d_in[0];
  const int*   ids      = (const int*)d_in[1];
  const float* w_qkv    = (const float*)d_in[2];
  const float* w_proj   = (const float*)d_in[3];
  const float* b_proj   = (const float*)d_in[4];
  const float* rel_tab  = (const float*)d_in[5];
  float* out = (float*)d_out;

  char* ws = (char*)d_ws;
  u16* xb   = (u16*)(ws);              // 8192x512 bf16 (8.39MB); later reused as attn_out
  u16* wT   = (u16*)(ws + 8388608);    // 1536x512 bf16
  u16* wpT  = (u16*)(ws + 9961472);    // 512x512 bf16
  u16* Qb   = (u16*)(ws + 10485760);   // (B,H,N,D) bf16, pre-scaled by 1/8
  u16* Kb   = (u16*)(ws + 18874368);   // (B,H,N,D) bf16
  u16* Vtb  = (u16*)(ws + 27262976);   // (B,H,D,N) bf16
  u16* attn = xb;                      // alias: xb dead after gemms

  cvt_to_bf16<<<4096, 256, 0, stream>>>(x, xb, 8 * 1024 * 512);
  transpose_to_bf16<<<dim3(48, 16), dim3(32, 8), 0, stream>>>(w_qkv, wT, 512, 1536);
  transpose_to_bf16<<<dim3(16, 16), dim3(32, 8), 0, stream>>>(w_proj, wpT, 512, 512);

  gemm_bt<0><<<dim3(64, 8), 256, 0, stream>>>(wT, xb, Qb, Kb, nullptr, nullptr);
  gemm_bt<1><<<dim3(4, 64), 256, 0, stream>>>(xb, wT + 1024 * 512, Vtb, nullptr, nullptr, nullptr);

  flash_attn<<<dim3(256), 512, 0, stream>>>(Qb, Kb, Vtb, ids, rel_tab, attn);

  gemm_bt<2><<<dim3(64, 4), 256, 0, stream>>>(wpT, attn, nullptr, nullptr, out, b_proj);
}

// Round 3
// 240.754 us; speedup vs baseline: 1.3944x; 1.0813x over previous
//
#include <hip/hip_runtime.h>

typedef __attribute__((ext_vector_type(8))) __bf16 bf16x8;
typedef __attribute__((ext_vector_type(4))) float f32x4;
typedef unsigned short u16;
typedef unsigned int u32;

__device__ __forceinline__ u16 f2bf(float f) {
  __bf16 h = (__bf16)f;   // compiler emits packed/scalar cvt (m240: faster than hand-rolled)
  return *(u16*)&h;
}
__device__ __forceinline__ f32x4 mfma16(bf16x8 a, bf16x8 b, f32x4 c) {
  return __builtin_amdgcn_mfma_f32_16x16x32_bf16(a, b, c, 0, 0, 0);
}

// ---------------- converts ----------------
__global__ void cvt_to_bf16(const float* __restrict__ src, u16* __restrict__ dst, int n) {
  const int i = (blockIdx.x * 256 + threadIdx.x) * 4;
  if (i + 3 < n) {
    const float4 v = *(const float4*)(src + i);
    ushort4 o; o.x = f2bf(v.x); o.y = f2bf(v.y); o.z = f2bf(v.z); o.w = f2bf(v.w);
    *(ushort4*)(dst + i) = o;
  }
}

// dst[C x R] = bf16(src[R x C])^T
__global__ void transpose_to_bf16(const float* __restrict__ src, u16* __restrict__ dst,
                                  int R, int C) {
  __shared__ float tile[32][33];
  const int c0 = blockIdx.x * 32, r0 = blockIdx.y * 32;
  const int tx = threadIdx.x, ty = threadIdx.y;
  for (int i = ty; i < 32; i += 8)
    tile[i][tx] = src[(size_t)(r0 + i) * C + c0 + tx];
  __syncthreads();
  for (int i = ty; i < 32; i += 8)
    dst[(size_t)(c0 + i) * R + r0 + tx] = f2bf(tile[tx][i]);
}

// ---------------- GEMM: C[MxN] = A[Mx512] * Bt[Nx512]^T, K=512 ----------------
template<int MODE>
__global__ __launch_bounds__(256, 2) void gemm_bt(
    const u16* __restrict__ A, const u16* __restrict__ Bt,
    u16* __restrict__ out0, u16* __restrict__ out1,
    float* __restrict__ fout, const float* __restrict__ bias)
{
  __shared__ u16 As[128][40];
  __shared__ u16 Bs[128][40];
  const int tid = threadIdx.x;
  const int w = tid >> 6, l = tid & 63;
  const int lr = l & 15, lg = l >> 4;
  const int wr = w >> 1, wc = w & 1;
  const int m0 = blockIdx.y * 128, n0 = blockIdx.x * 128;

  f32x4 acc[4][4] = {};

  for (int k0 = 0; k0 < 512; k0 += 32) {
    int4 ra[2], rb[2];
#pragma unroll
    for (int it = 0; it < 2; ++it) {
      const int ch = it * 256 + tid;
      const int row = ch >> 2, c = ch & 3;
      ra[it] = *(const int4*)(A  + (size_t)(m0 + row) * 512 + k0 + c * 8);
      rb[it] = *(const int4*)(Bt + (size_t)(n0 + row) * 512 + k0 + c * 8);
    }
    __syncthreads();
#pragma unroll
    for (int it = 0; it < 2; ++it) {
      const int ch = it * 256 + tid;
      const int row = ch >> 2, c = ch & 3;
      *(int4*)&As[row][c * 8] = ra[it];
      *(int4*)&Bs[row][c * 8] = rb[it];
    }
    __syncthreads();
    bf16x8 af[4], bfr[4];
#pragma unroll
    for (int mi = 0; mi < 4; ++mi)
      af[mi] = *(const bf16x8*)&As[wr * 64 + mi * 16 + lr][lg * 8];
#pragma unroll
    for (int nj = 0; nj < 4; ++nj)
      bfr[nj] = *(const bf16x8*)&Bs[wc * 64 + nj * 16 + lr][lg * 8];
#pragma unroll
    for (int mi = 0; mi < 4; ++mi)
#pragma unroll
      for (int nj = 0; nj < 4; ++nj)
        acc[mi][nj] = mfma16(af[mi], bfr[nj], acc[mi][nj]);
  }

#pragma unroll
  for (int mi = 0; mi < 4; ++mi)
#pragma unroll
    for (int nj = 0; nj < 4; ++nj) {
      const int i0 = m0 + wr * 64 + mi * 16 + lg * 4;
      const int j  = n0 + wc * 64 + nj * 16 + lr;
      if (MODE == 0) {
        const int bb = j >> 10, n = j & 1023;
        const bool isQ = i0 < 512;
        const int f = isQ ? i0 : i0 - 512;
        const int h = f >> 6, d = f & 63;
        const float scl = isQ ? 0.125f : 1.0f;
        u16* dst = isQ ? out0 : out1;
        ushort4 o;
        o.x = f2bf(acc[mi][nj][0] * scl); o.y = f2bf(acc[mi][nj][1] * scl);
        o.z = f2bf(acc[mi][nj][2] * scl); o.w = f2bf(acc[mi][nj][3] * scl);
        *(ushort4*)(dst + ((size_t)((bb * 8 + h) * 1024 + n)) * 64 + d) = o;
      } else if (MODE == 1) {
        const int bb = i0 >> 10, nloc = i0 & 1023;
        const int h = j >> 6, d = j & 63;
        ushort4 o;
        o.x = f2bf(acc[mi][nj][0]); o.y = f2bf(acc[mi][nj][1]);
        o.z = f2bf(acc[mi][nj][2]); o.w = f2bf(acc[mi][nj][3]);
        *(ushort4*)(out0 + ((size_t)((bb * 8 + h) * 64 + d)) * 1024 + nloc) = o;
      } else {
        const float4 bp = *(const float4*)(bias + i0);
        float4 o;
        o.x = acc[mi][nj][0] + bp.x; o.y = acc[mi][nj][1] + bp.y;
        o.z = acc[mi][nj][2] + bp.z; o.w = acc[mi][nj][3] + bp.w;
        *(float4*)(fout + (size_t)j * 512 + i0) = o;
      }
    }
}

// ---------------- flash attention ----------------
// grid = B*32*2 (b, 32-row q-tile, head-half); 256 threads = 4 waves = 4 heads.
// Pipelined: iteration t prefetches K/V(t+1) into regs and bias(t+1) into
// double-buffered fp32 LDS. One barrier per iteration.
__global__ __launch_bounds__(256, 2) void flash_attn(
    const u16* __restrict__ Q, const u16* __restrict__ Kg,
    const u16* __restrict__ Vt, const int* __restrict__ ids_keep,
    const float* __restrict__ rel_table,
    u16* __restrict__ attn_out)
{
  __shared__ float Bi[2][4][32][34];   // [buf][head][n][m], fp32, pad->2-way free
  __shared__ u16 Ps[4][32][40];        // per head P tile [n][m]
  __shared__ int codes_s[1024];

  const int bb   = blockIdx.x >> 6;
  const int n0   = ((blockIdx.x >> 1) & 31) << 5;
  const int half = blockIdx.x & 1;
  const int tid = threadIdx.x;
  const int w = tid >> 6;
  const int l = tid & 63;
  const int lr = l & 15, lg = l >> 4;
  const int h = half * 4 + w;

#pragma unroll
  for (int s = 0; s < 4; ++s) {
    const int id = ids_keep[bb * 1024 + s * 256 + tid];
    codes_s[s * 256 + tid] = (id >> 6) * 127 + (id & 63);
  }

  const size_t hbase = (size_t)(bb * 8 + h) * (1024 * 64);

  bf16x8 qf[2][2];
#pragma unroll
  for (int mi = 0; mi < 2; ++mi)
#pragma unroll
    for (int ki = 0; ki < 2; ++ki)
      qf[mi][ki] = *(const bf16x8*)(Q + hbase + (size_t)(n0 + mi * 16 + lr) * 64 + ki * 32 + lg * 8);

  f32x4 acc[2][4] = {};
  float mrow[2][4], lsum[2][4];
#pragma unroll
  for (int mi = 0; mi < 2; ++mi)
#pragma unroll
    for (int r = 0; r < 4; ++r) { mrow[mi][r] = -1e30f; lsum[mi][r] = 0.f; }

  __syncthreads();   // codes ready

  bf16x8 kfA[2][2], vfA[4], kfB[2][2], vfB[4];

  // prologue: K/V(0) + bias(0)
#pragma unroll
  for (int mj = 0; mj < 2; ++mj)
#pragma unroll
    for (int ki = 0; ki < 2; ++ki)
      kfA[mj][ki] = *(const bf16x8*)(Kg + hbase + (size_t)(mj * 16 + lr) * 64 + ki * 32 + lg * 8);
#pragma unroll
  for (int dj = 0; dj < 4; ++dj)
    vfA[dj] = *(const bf16x8*)(Vt + hbase + (size_t)(dj * 16 + lr) * 1024 + 0 + lg * 8);
  {
    float4 g[4]; int pns[4], pms[4];
#pragma unroll
    for (int s = 0; s < 4; ++s) {
      const int p = s * 256 + tid;
      pns[s] = p >> 5; pms[s] = p & 31;
      const int idx = codes_s[n0 + pns[s]] - codes_s[pms[s]] + 8064;
      g[s] = *(const float4*)(rel_table + (size_t)idx * 8 + half * 4);
    }
#pragma unroll
    for (int s = 0; s < 4; ++s) {
      Bi[0][0][pns[s]][pms[s]] = g[s].x;
      Bi[0][1][pns[s]][pms[s]] = g[s].y;
      Bi[0][2][pns[s]][pms[s]] = g[s].z;
      Bi[0][3][pns[s]][pms[s]] = g[s].w;
    }
  }
  __syncthreads();

  auto body = [&](int t, int bufc, bf16x8 (&kfc)[2][2], bf16x8 (&vfc)[4],
                  bf16x8 (&kfn)[2][2], bf16x8 (&vfn)[4]) {
    const bool pf = (t + 1) < 32;
    float4 g[4]; int pns[4], pms[4];
    if (pf) {
      const int m1 = (t + 1) << 5;
#pragma unroll
      for (int mj = 0; mj < 2; ++mj)
#pragma unroll
        for (int ki = 0; ki < 2; ++ki)
          kfn[mj][ki] = *(const bf16x8*)(Kg + hbase + (size_t)(m1 + mj * 16 + lr) * 64 + ki * 32 + lg * 8);
#pragma unroll
      for (int dj = 0; dj < 4; ++dj)
        vfn[dj] = *(const bf16x8*)(Vt + hbase + (size_t)(dj * 16 + lr) * 1024 + m1 + lg * 8);
#pragma unroll
      for (int s = 0; s < 4; ++s) {
        const int p = s * 256 + tid;
        pns[s] = p >> 5; pms[s] = p & 31;
        const int idx = codes_s[n0 + pns[s]] - codes_s[m1 + pms[s]] + 8064;
        g[s] = *(const float4*)(rel_table + (size_t)idx * 8 + half * 4);
      }
    }

    // QK^T
    f32x4 sc[2][2];
#pragma unroll
    for (int mi = 0; mi < 2; ++mi)
#pragma unroll
      for (int mj = 0; mj < 2; ++mj) {
        f32x4 z = {};
        z = mfma16(qf[mi][0], kfc[mj][0], z);
        sc[mi][mj] = mfma16(qf[mi][1], kfc[mj][1], z);
      }

    // bias add (fp32 LDS)
#pragma unroll
    for (int mi = 0; mi < 2; ++mi)
#pragma unroll
      for (int mj = 0; mj < 2; ++mj)
#pragma unroll
        for (int r = 0; r < 4; ++r)
          sc[mi][mj][r] += Bi[bufc][w][mi * 16 + lg * 4 + r][mj * 16 + lr];

    // online softmax with defer-max (T13)
#pragma unroll
    for (int mi = 0; mi < 2; ++mi) {
      float tm[4];
#pragma unroll
      for (int r = 0; r < 4; ++r) {
        tm[r] = fmaxf(sc[mi][0][r], sc[mi][1][r]);
#pragma unroll
        for (int off = 1; off < 16; off <<= 1)
          tm[r] = fmaxf(tm[r], __shfl_xor(tm[r], off));
      }
      float need = tm[0] - mrow[mi][0];
#pragma unroll
      for (int r = 1; r < 4; ++r) need = fmaxf(need, tm[r] - mrow[mi][r]);
      if (!__all(need <= 8.f)) {
        float co[4];
#pragma unroll
        for (int r = 0; r < 4; ++r) {
          const float mn = fmaxf(mrow[mi][r], tm[r]);
          co[r] = __expf(mrow[mi][r] - mn);
          mrow[mi][r] = mn;
          lsum[mi][r] *= co[r];
        }
#pragma unroll
        for (int dj = 0; dj < 4; ++dj)
#pragma unroll
          for (int r = 0; r < 4; ++r)
            acc[mi][dj][r] *= co[r];
      }
#pragma unroll
      for (int mj = 0; mj < 2; ++mj)
#pragma unroll
        for (int r = 0; r < 4; ++r)
          sc[mi][mj][r] = __expf(sc[mi][mj][r] - mrow[mi][r]);
      float ts[4];
#pragma unroll
      for (int r = 0; r < 4; ++r) {
        ts[r] = sc[mi][0][r] + sc[mi][1][r];
#pragma unroll
        for (int off = 1; off < 16; off <<= 1)
          ts[r] += __shfl_xor(ts[r], off);
        lsum[mi][r] += ts[r];
      }
    }

    // P -> LDS (wave-local, no barrier needed)
#pragma unroll
    for (int mi = 0; mi < 2; ++mi)
#pragma unroll
      for (int mj = 0; mj < 2; ++mj)
#pragma unroll
        for (int r = 0; r < 4; ++r)
          Ps[w][mi * 16 + lg * 4 + r][mj * 16 + lr] = f2bf(sc[mi][mj][r]);

    // PV
    bf16x8 pa[2];
#pragma unroll
    for (int mi = 0; mi < 2; ++mi)
      pa[mi] = *(const bf16x8*)&Ps[w][mi * 16 + lr][lg * 8];
#pragma unroll
    for (int mi = 0; mi < 2; ++mi)
#pragma unroll
      for (int dj = 0; dj < 4; ++dj)
        acc[mi][dj] = mfma16(pa[mi], vfc[dj], acc[mi][dj]);

    // commit next-iter bias to other buffer
    if (pf) {
      const int bufn = bufc ^ 1;
#pragma unroll
      for (int s = 0; s < 4; ++s) {
        Bi[bufn][0][pns[s]][pms[s]] = g[s].x;
        Bi[bufn][1][pns[s]][pms[s]] = g[s].y;
        Bi[bufn][2][pns[s]][pms[s]] = g[s].z;
        Bi[bufn][3][pns[s]][pms[s]] = g[s].w;
      }
    }
    __syncthreads();
  };

  for (int tt = 0; tt < 32; tt += 2) {
    body(tt,     0, kfA, vfA, kfB, vfB);
    body(tt + 1, 1, kfB, vfB, kfA, vfA);
  }

#pragma unroll
  for (int mi = 0; mi < 2; ++mi) {
    float inv[4];
#pragma unroll
    for (int r = 0; r < 4; ++r) inv[r] = 1.0f / lsum[mi][r];
#pragma unroll
    for (int dj = 0; dj < 4; ++dj)
#pragma unroll
      for (int r = 0; r < 4; ++r)
        attn_out[(size_t)(bb * 1024 + n0 + mi * 16 + lg * 4 + r) * 512 + h * 64 + dj * 16 + lr] =
            f2bf(acc[mi][dj][r] * inv[r]);
  }
}

// ---------------- launch ----------------
extern "C" void kernel_launch(void* const* d_in, const int* in_sizes, int n_in,
                              void* d_out, int out_size, void* d_ws, size_t ws_size,
                              hipStream_t stream) {
  const float* x        = (const float*)d_in[0];
  const int*   ids      = (const int*)d_in[1];
  const float* w_qkv    = (const float*)d_in[2];
  const float* w_proj   = (const float*)d_in[3];
  const float* b_proj   = (const float*)d_in[4];
  const float* rel_tab  = (const float*)d_in[5];
  float* out = (float*)d_out;

  char* ws = (char*)d_ws;
  u16* xb   = (u16*)(ws);              // 8192x512 bf16; later reused as attn_out
  u16* wT   = (u16*)(ws + 8388608);    // 1536x512 bf16
  u16* wpT  = (u16*)(ws + 9961472);    // 512x512 bf16
  u16* Qb   = (u16*)(ws + 10485760);   // (B,H,N,D) bf16, pre-scaled by 1/8
  u16* Kb   = (u16*)(ws + 18874368);   // (B,H,N,D) bf16
  u16* Vtb  = (u16*)(ws + 27262976);   // (B,H,D,N) bf16
  u16* attn = xb;

  cvt_to_bf16<<<4096, 256, 0, stream>>>(x, xb, 8 * 1024 * 512);
  transpose_to_bf16<<<dim3(48, 16), dim3(32, 8), 0, stream>>>(w_qkv, wT, 512, 1536);
  transpose_to_bf16<<<dim3(16, 16), dim3(32, 8), 0, stream>>>(w_proj, wpT, 512, 512);

  gemm_bt<0><<<dim3(64, 8), 256, 0, stream>>>(wT, xb, Qb, Kb, nullptr, nullptr);
  gemm_bt<1><<<dim3(4, 64), 256, 0, stream>>>(xb, wT + 1024 * 512, Vtb, nullptr, nullptr, nullptr);

  flash_attn<<<dim3(512), 256, 0, stream>>>(Qb, Kb, Vtb, ids, rel_tab, attn);

  gemm_bt<2><<<dim3(64, 4), 256, 0, stream>>>(wpT, attn, nullptr, nullptr, out, b_proj);
}